// Round 9
// baseline (65.818 us; speedup 1.0000x reference)
//
#include <hip/hip_runtime.h>

typedef unsigned short u16;
typedef __attribute__((ext_vector_type(8))) __bf16 bf16x8;
typedef __attribute__((ext_vector_type(4))) float f32x4;

#define GLOAD_LDS16(g, l)                                                                     \
  __builtin_amdgcn_global_load_lds((const __attribute__((address_space(1))) unsigned int*)(g), \
                                   (__attribute__((address_space(3))) unsigned int*)(l), 16, 0, 0)

static __device__ __forceinline__ u16 f2bf(float f) {
  unsigned int u = __float_as_uint(f);
  u += 0x7fffu + ((u >> 16) & 1u);   // round-to-nearest-even
  return (u16)(u >> 16);
}

// Problem constants
#define BATCH 32
#define NN 1024   // transform length
#define MM 512    // columns
#define KH 512    // half transform length (folded K)

// Dual-bijective LDS chunk swizzle: bijective on row-step-1 (frag reads) AND
// row-step-2 (X transpose writes). Verified by enumeration in the analysis.
static __device__ __forceinline__ int swz(int r) { return ((r >> 1) ^ ((r & 1) << 2)) & 7; }

// ---- kernel 1: pre-swizzled interleaved E|O matrix ----
// G[j][s][64]: row-of-64 per (j in [0,512), K-step s in [0,16)).
// Physical chunk cp (0..7) of 8 u16 holds data chunk = cp ^ swz(j):
//   chunk<4: E part, p = s*32 + chunk*8 + sub  -> M[j][2p]
//   chunk>=4: O part, p = s*32 + (chunk-4)*8 + sub -> M[j][2p+1]
// M[j][k] = (k==0 ? 1/32 : sqrt(2/1024)*cos(pi*k*(2j+1)/2048))
__global__ void fill_g(u16* __restrict__ G) {
  int idx = blockIdx.x * 256 + threadIdx.x;  // 512*1024
  int j = idx >> 10;
  int r = idx & 1023;
  int s = r >> 6;
  int cp = (r >> 3) & 7;
  int sub = r & 7;
  int chunk = cp ^ swz(j);
  int k;
  if (chunk < 4) k = 2 * (s * 32 + chunk * 8 + sub);
  else           k = 2 * (s * 32 + (chunk - 4) * 8 + sub) + 1;
  float v;
  if (k == 0) {
    v = 0.03125f;  // 1/sqrt(1024)
  } else {
    int ph = (k * (2 * j + 1)) & 4095;
    v = 0.04419417382415922f * cosf((float)ph * 1.5339807878856412e-3f);
  }
  G[idx] = f2bf(v);
}

// ---- kernel 2: fused symmetry-halved GEMM, transpose/split in-kernel ----
// out[j] = (E.Xe + O.Xo)[j], out[1023-j] = (E.Xe - O.Xo)[j], j in [0,512).
// A: G staged via linear global_load_lds (pre-swizzled at fill), dbuf by step parity.
// X: x[b][k][c] f32 read as float2 (coalesced 512B/wave), cvt->bf16, transposing
//    swizzled ds_write_b128 into sX[c][Xe 0..31 | Xo 32..63], single-buffered.
// Step s (BK=32 p / 64 k), plain __syncthreads only:
//   WRITE_X(s from regs) ; barrier1 (lgkm only) ;
//   issue A(s+1)+X(s+1) loads ; frag reads + 32 MFMA ; barrier2 (drains loads).
// WAR on xr regs is barrier-separated; sX write-after-read separated by barrier2(s-1).
// XCD decode (R5-verified): 4 tm-sharers of each (tn,b) x-panel share wg&7.
__global__ __launch_bounds__(256, 3) void gemm_idct(const u16* __restrict__ G,
                                                    const float* __restrict__ X,
                                                    float* __restrict__ C) {
  __shared__ __align__(16) u16 sA[2][128 * 64];  // 2 x 16 KiB (E|O chunk-interleaved)
  __shared__ __align__(16) u16 sX[128 * 64];     // 16 KiB (Xe|Xo chunk-interleaved)
  // --- XCD-aware decode ---
  const int wg   = blockIdx.x;
  const int xcd  = wg & 7;
  const int slot = wg >> 3;
  const int tm   = slot & 3;                 // j tile 0..3 (128 rows)
  const int pair = ((slot >> 2) << 3) | xcd; // 0..127
  const int tn   = pair & 3;                 // c tile 0..3 (128 cols)
  const int b    = pair >> 2;                // batch 0..31

  const int t = threadIdx.x;
  const int wave = t >> 6, lane = t & 63;
  const int wr = wave >> 1, wc = wave & 1;   // 2x2 waves, 64x64 out each
  const int lhi = lane >> 4, llo = lane & 15;

  // --- A staging: call c stages rows c*32..c*32+31; source is linear in G ---
  const u16* srcA = G + ((size_t)(tm * 128 + (t >> 3)) << 10) + (t & 7) * 8;
#define ISSUE_A(s)                                                             \
  do {                                                                         \
    u16* dst = &sA[(s) & 1][0];                                                \
    _Pragma("unroll") for (int c = 0; c < 4; ++c)                              \
      GLOAD_LDS16(srcA + c * 32768 + (s) * 64, dst + c * 2048 + t * 8);        \
  } while (0)

  // --- X staging map: thread owns c in {2cp, 2cp+1}, k in [kq*16, kq*16+16) ---
  const int cp2 = (t & 63) << 1;  // c base (0..126 step 2)
  const int kq  = t >> 6;         // k quarter 0..3
  const float* gX = X + ((size_t)b * NN + kq * 16) * MM + tn * 128 + cp2;

  float2 xr[16];
#define LOAD_X(s)                                                              \
  do {                                                                         \
    const float* p = gX + (size_t)(s) * 64 * MM;                               \
    _Pragma("unroll") for (int i = 0; i < 16; ++i)                             \
      xr[i] = *(const float2*)(p + (size_t)i * MM);                            \
  } while (0)

#define WRITE_X()                                                              \
  do {                                                                         \
    _Pragma("unroll") for (int cc = 0; cc < 2; ++cc) {                         \
      const int c = cp2 + cc;                                                  \
      const int fc = swz(c);                                                   \
      bf16x8 e, o;                                                             \
      _Pragma("unroll") for (int m = 0; m < 8; ++m) {                          \
        e[m] = (__bf16)(cc ? xr[2 * m].y : xr[2 * m].x);                       \
        o[m] = (__bf16)(cc ? xr[2 * m + 1].y : xr[2 * m + 1].x);               \
      }                                                                        \
      *(bf16x8*)&sX[c * 64 + ((kq ^ fc) << 3)] = e;                            \
      *(bf16x8*)&sX[c * 64 + (((4 + kq) ^ fc) << 3)] = o;                      \
    }                                                                          \
  } while (0)

  f32x4 accE[4][4] = {};
  f32x4 accO[4][4] = {};

  // ---- prologue: stage step 0 ----
  ISSUE_A(0);
  LOAD_X(0);
  __syncthreads();  // drain A(0) + X(0)

  for (int s = 0; s < 16; ++s) {
    WRITE_X();        // sX <- step s (regs loaded at s-1, long since drained)
    __syncthreads();  // barrier1: ds_writes visible; no vm outstanding
    if (s < 15) {
      ISSUE_A(s + 1);  // -> sA[(s+1)&1], free since (s-1)'s barrier2
      LOAD_X(s + 1);   // xr overwrite: program-order after WRITE_X's reads
    }
    const u16* lA = &sA[s & 1][0];
    bf16x8 fe[4], fo[4], fxe[4], fxo[4];
#pragma unroll
    for (int i = 0; i < 4; ++i) {
      const int ra = wr * 64 + i * 16 + llo;
      const int rb = wc * 64 + i * 16 + llo;
      const int fa = swz(ra), fb = swz(rb);
      fe[i]  = *(const bf16x8*)&lA[ra * 64 + ((lhi ^ fa) << 3)];
      fo[i]  = *(const bf16x8*)&lA[ra * 64 + (((4 + lhi) ^ fa) << 3)];
      fxe[i] = *(const bf16x8*)&sX[rb * 64 + ((lhi ^ fb) << 3)];
      fxo[i] = *(const bf16x8*)&sX[rb * 64 + (((4 + lhi) ^ fb) << 3)];
    }
#pragma unroll
    for (int mi = 0; mi < 4; ++mi)
#pragma unroll
      for (int ni = 0; ni < 4; ++ni)
        accE[mi][ni] = __builtin_amdgcn_mfma_f32_16x16x32_bf16(
            fe[mi], fxe[ni], accE[mi][ni], 0, 0, 0);
#pragma unroll
    for (int mi = 0; mi < 4; ++mi)
#pragma unroll
      for (int ni = 0; ni < 4; ++ni)
        accO[mi][ni] = __builtin_amdgcn_mfma_f32_16x16x32_bf16(
            fo[mi], fxo[ni], accO[mi][ni], 0, 0, 0);
    __syncthreads();  // barrier2: drains A(s+1)+X(s+1) (full-phase flight)
  }

  // ---- epilogue: out[j] = Ye+Yo, out[1023-j] = Ye-Yo ----
  // C/D layout (m89-verified): col = lane&15, row = (lane>>4)*4 + reg
  float* Cb = C + (size_t)b * NN * MM;
  const int jhbase = tm * 128 + wr * 64 + lhi * 4;
  const int cbase  = tn * 128 + wc * 64 + llo;
#pragma unroll
  for (int mi = 0; mi < 4; ++mi)
#pragma unroll
    for (int ni = 0; ni < 4; ++ni) {
      const int jh = jhbase + mi * 16;
      const int c  = cbase + ni * 16;
#pragma unroll
      for (int r = 0; r < 4; ++r) {
        const float ye = accE[mi][ni][r];
        const float yo = accO[mi][ni][r];
        Cb[(size_t)(jh + r) * MM + c]            = ye + yo;
        Cb[(size_t)(NN - 1 - (jh + r)) * MM + c] = ye - yo;
      }
    }
#undef ISSUE_A
#undef LOAD_X
#undef WRITE_X
}

extern "C" void kernel_launch(void* const* d_in, const int* in_sizes, int n_in,
                              void* d_out, int out_size, void* d_ws, size_t ws_size,
                              hipStream_t stream) {
  const float* x = (const float*)d_in[0];
  float* out = (float*)d_out;
  u16* G = (u16*)d_ws;  // 512*1024 u16 = 1 MiB

  fill_g<<<dim3((512 * 1024) / 256), dim3(256), 0, stream>>>(G);
  gemm_idct<<<dim3(512), dim3(256), 0, stream>>>(G, x, out);
}

// Round 10
// 46.072 us; speedup vs baseline: 1.4286x; 1.4286x over previous
//
#include <hip/hip_runtime.h>

typedef unsigned short u16;
typedef __attribute__((ext_vector_type(8))) __bf16 bf16x8;
typedef __attribute__((ext_vector_type(4))) float f32x4;

#define GLOAD_LDS16(g, l)                                                                     \
  __builtin_amdgcn_global_load_lds((const __attribute__((address_space(1))) unsigned int*)(g), \
                                   (__attribute__((address_space(3))) unsigned int*)(l), 16, 0, 0)

static __device__ __forceinline__ u16 f2bf(float f) {
  unsigned int u = __float_as_uint(f);
  u += 0x7fffu + ((u >> 16) & 1u);   // round-to-nearest-even
  return (u16)(u >> 16);
}

// Problem constants
#define BATCH 32
#define NN 1024   // transform length
#define MM 512    // columns
#define KH 512    // half transform length (folded K)

// Dual-bijective LDS chunk swizzle: bijective on row-step-1 (frag reads) AND
// row-step-2 (X transpose writes). Verified by enumeration.
static __device__ __forceinline__ int swz(int r) { return ((r >> 1) ^ ((r & 1) << 2)) & 7; }

// ---- kernel 1: pre-swizzled interleaved E|O matrix ----
// G[j][s][64]: row-of-64 per (j in [0,512), K-step s in [0,16)).
// Physical chunk cp (0..7) holds data chunk = cp ^ swz(j):
//   chunk<4: E part, p = s*32 + chunk*8 + sub  -> M[j][2p]
//   chunk>=4: O part, p = s*32 + (chunk-4)*8 + sub -> M[j][2p+1]
__global__ void fill_g(u16* __restrict__ G) {
  int idx = blockIdx.x * 256 + threadIdx.x;  // 512*1024
  int j = idx >> 10;
  int r = idx & 1023;
  int s = r >> 6;
  int cp = (r >> 3) & 7;
  int sub = r & 7;
  int chunk = cp ^ swz(j);
  int k;
  if (chunk < 4) k = 2 * (s * 32 + chunk * 8 + sub);
  else           k = 2 * (s * 32 + (chunk - 4) * 8 + sub) + 1;
  float v;
  if (k == 0) {
    v = 0.03125f;  // 1/sqrt(1024)
  } else {
    int ph = (k * (2 * j + 1)) & 4095;
    v = 0.04419417382415922f * cosf((float)ph * 1.5339807878856412e-3f);
  }
  G[idx] = f2bf(v);
}

// ---- kernel 2: fused symmetry-halved GEMM, transpose/split in-kernel ----
// out[j] = (E.Xe + O.Xo)[j], out[1023-j] = (E.Xe - O.Xo)[j], j in [0,512).
// Identical to round 9 EXCEPT __launch_bounds__(256, 2): round 9's (256,3)
// capped VGPRs at 84 < the 128 accumulator registers -> acc spilled to scratch
// (the MfmaUtil-8% catastrophe). Grid = 512 blocks = 2 blocks/CU anyway.
__global__ __launch_bounds__(256, 2) void gemm_idct(const u16* __restrict__ G,
                                                    const float* __restrict__ X,
                                                    float* __restrict__ C) {
  __shared__ __align__(16) u16 sA[2][128 * 64];  // 2 x 16 KiB (E|O chunk-interleaved)
  __shared__ __align__(16) u16 sX[128 * 64];     // 16 KiB (Xe|Xo chunk-interleaved)
  // --- XCD-aware decode ---
  const int wg   = blockIdx.x;
  const int xcd  = wg & 7;
  const int slot = wg >> 3;
  const int tm   = slot & 3;                 // j tile 0..3 (128 rows)
  const int pair = ((slot >> 2) << 3) | xcd; // 0..127
  const int tn   = pair & 3;                 // c tile 0..3 (128 cols)
  const int b    = pair >> 2;                // batch 0..31

  const int t = threadIdx.x;
  const int wave = t >> 6, lane = t & 63;
  const int wr = wave >> 1, wc = wave & 1;   // 2x2 waves, 64x64 out each
  const int lhi = lane >> 4, llo = lane & 15;

  // --- A staging: call c stages rows c*32..c*32+31; source is linear in G ---
  const u16* srcA = G + ((size_t)(tm * 128 + (t >> 3)) << 10) + (t & 7) * 8;
#define ISSUE_A(s)                                                             \
  do {                                                                         \
    u16* dst = &sA[(s) & 1][0];                                                \
    _Pragma("unroll") for (int c = 0; c < 4; ++c)                              \
      GLOAD_LDS16(srcA + c * 32768 + (s) * 64, dst + c * 2048 + t * 8);        \
  } while (0)

  // --- X staging map: thread owns c in {2cp, 2cp+1}, k in [kq*16, kq*16+16) ---
  const int cp2 = (t & 63) << 1;  // c base (0..126 step 2)
  const int kq  = t >> 6;         // k quarter 0..3
  const float* gX = X + ((size_t)b * NN + kq * 16) * MM + tn * 128 + cp2;

  float2 xr[16];
#define LOAD_X(s)                                                              \
  do {                                                                         \
    const float* p = gX + (size_t)(s) * 64 * MM;                               \
    _Pragma("unroll") for (int i = 0; i < 16; ++i)                             \
      xr[i] = *(const float2*)(p + (size_t)i * MM);                            \
  } while (0)

#define WRITE_X()                                                              \
  do {                                                                         \
    _Pragma("unroll") for (int cc = 0; cc < 2; ++cc) {                         \
      const int c = cp2 + cc;                                                  \
      const int fc = swz(c);                                                   \
      bf16x8 e, o;                                                             \
      _Pragma("unroll") for (int m = 0; m < 8; ++m) {                          \
        e[m] = (__bf16)(cc ? xr[2 * m].y : xr[2 * m].x);                       \
        o[m] = (__bf16)(cc ? xr[2 * m + 1].y : xr[2 * m + 1].x);               \
      }                                                                        \
      *(bf16x8*)&sX[c * 64 + ((kq ^ fc) << 3)] = e;                            \
      *(bf16x8*)&sX[c * 64 + (((4 + kq) ^ fc) << 3)] = o;                      \
    }                                                                          \
  } while (0)

  f32x4 accE[4][4] = {};
  f32x4 accO[4][4] = {};

  // ---- prologue: stage step 0 ----
  ISSUE_A(0);
  LOAD_X(0);
  __syncthreads();  // drain A(0) + X(0)

  for (int s = 0; s < 16; ++s) {
    WRITE_X();        // sX <- step s (regs loaded at s-1, long since drained)
    __syncthreads();  // barrier1: ds_writes visible
    if (s < 15) {
      ISSUE_A(s + 1);  // -> sA[(s+1)&1], free since (s-1)'s barrier2
      LOAD_X(s + 1);   // xr overwrite: program-order after WRITE_X's reads
    }
    const u16* lA = &sA[s & 1][0];
    bf16x8 fe[4], fo[4], fxe[4], fxo[4];
#pragma unroll
    for (int i = 0; i < 4; ++i) {
      const int ra = wr * 64 + i * 16 + llo;
      const int rb = wc * 64 + i * 16 + llo;
      const int fa = swz(ra), fb = swz(rb);
      fe[i]  = *(const bf16x8*)&lA[ra * 64 + ((lhi ^ fa) << 3)];
      fo[i]  = *(const bf16x8*)&lA[ra * 64 + (((4 + lhi) ^ fa) << 3)];
      fxe[i] = *(const bf16x8*)&sX[rb * 64 + ((lhi ^ fb) << 3)];
      fxo[i] = *(const bf16x8*)&sX[rb * 64 + (((4 + lhi) ^ fb) << 3)];
    }
#pragma unroll
    for (int mi = 0; mi < 4; ++mi)
#pragma unroll
      for (int ni = 0; ni < 4; ++ni)
        accE[mi][ni] = __builtin_amdgcn_mfma_f32_16x16x32_bf16(
            fe[mi], fxe[ni], accE[mi][ni], 0, 0, 0);
#pragma unroll
    for (int mi = 0; mi < 4; ++mi)
#pragma unroll
      for (int ni = 0; ni < 4; ++ni)
        accO[mi][ni] = __builtin_amdgcn_mfma_f32_16x16x32_bf16(
            fo[mi], fxo[ni], accO[mi][ni], 0, 0, 0);
    __syncthreads();  // barrier2: drains A(s+1)+X(s+1)
  }

  // ---- epilogue: out[j] = Ye+Yo, out[1023-j] = Ye-Yo ----
  // C/D layout (m89-verified): col = lane&15, row = (lane>>4)*4 + reg
  float* Cb = C + (size_t)b * NN * MM;
  const int jhbase = tm * 128 + wr * 64 + lhi * 4;
  const int cbase  = tn * 128 + wc * 64 + llo;
#pragma unroll
  for (int mi = 0; mi < 4; ++mi)
#pragma unroll
    for (int ni = 0; ni < 4; ++ni) {
      const int jh = jhbase + mi * 16;
      const int c  = cbase + ni * 16;
#pragma unroll
      for (int r = 0; r < 4; ++r) {
        const float ye = accE[mi][ni][r];
        const float yo = accO[mi][ni][r];
        Cb[(size_t)(jh + r) * MM + c]            = ye + yo;
        Cb[(size_t)(NN - 1 - (jh + r)) * MM + c] = ye - yo;
      }
    }
#undef ISSUE_A
#undef LOAD_X
#undef WRITE_X
}

extern "C" void kernel_launch(void* const* d_in, const int* in_sizes, int n_in,
                              void* d_out, int out_size, void* d_ws, size_t ws_size,
                              hipStream_t stream) {
  const float* x = (const float*)d_in[0];
  float* out = (float*)d_out;
  u16* G = (u16*)d_ws;  // 512*1024 u16 = 1 MiB

  fill_g<<<dim3((512 * 1024) / 256), dim3(256), 0, stream>>>(G);
  gemm_idct<<<dim3(512), dim3(256), 0, stream>>>(G, x, out);
}